// Round 6
// baseline (120.384 us; speedup 1.0000x reference)
//
#include <hip/hip_runtime.h>
#include <cstdint>
#include <cstddef>

#define THETA 1.2f
#define XI 0.3f
#define BDIM 8192
#define DDIM 512
#define NTILE 64           // 64x64 grid of 128x128 tiles
#define NUPPER 2080        // NTILE*(NTILE+1)/2 upper-triangle block-tiles
#define GRID 1024          // 2-3 tiles per block; fills 3-4 blocks/CU occupancy
// upper-triangle-with-diagonal pair count: B*(B+1)/2
#define NPAIRS_UP (((double)BDIM * (double)(BDIM + 1)) * 0.5)

typedef float f32x4 __attribute__((ext_vector_type(4)));
typedef int i32x8 __attribute__((ext_vector_type(8)));

// ---------------------------------------------------------------------------
// Fragment-major ("tiled") fp8 layout:
//   frag F = (row/16)*4 + (kbyte/128)   -- 16 rows x 128 B of K = one MFMA frag
//   blob of 2048 B at F*2048; within blob, lane l = (row%16) + 16*((kbyte%128)/32)
//   holds its 32 B at offset l*32  -- exactly the mfma_scale 16x16x128 operand
//   order. A frag load = contiguous 2 KB per wave (8 full cachelines/instr).
// ---------------------------------------------------------------------------

// Kernel 1: per-row L2 normalize fp32 -> fp8 e4m3 into tiled layout;
// sq[row]=||n||^2; zero counter.
__global__ __launch_bounds__(256) void normalize_rows(
    const float* __restrict__ x, unsigned char* __restrict__ nf8,
    float* __restrict__ sq, unsigned int* __restrict__ counter)
{
    if (blockIdx.x == 0 && threadIdx.x == 0) { *counter = 0u; }
    int row = blockIdx.x * 4 + (threadIdx.x >> 6);
    int l = threadIdx.x & 63;
    const float4* xr = (const float4*)(x + (size_t)row * DDIM);
    float4 f0 = xr[l];
    float4 f1 = xr[l + 64];
    float s = f0.x*f0.x + f0.y*f0.y + f0.z*f0.z + f0.w*f0.w
            + f1.x*f1.x + f1.y*f1.y + f1.z*f1.z + f1.w*f1.w;
    #pragma unroll
    for (int m = 1; m < 64; m <<= 1) s += __shfl_xor(s, m);
    float rn = rsqrtf(s);
    int pk0 = __builtin_amdgcn_cvt_pk_fp8_f32(f0.x * rn, f0.y * rn, 0, false);
    pk0     = __builtin_amdgcn_cvt_pk_fp8_f32(f0.z * rn, f0.w * rn, pk0, true);
    int pk1 = __builtin_amdgcn_cvt_pk_fp8_f32(f1.x * rn, f1.y * rn, 0, false);
    pk1     = __builtin_amdgcn_cvt_pk_fp8_f32(f1.z * rn, f1.w * rn, pk1, true);
    // tiled scatter: pk0 covers k=[4l,4l+4), pk1 covers k=[4l+256,4l+260)
    size_t base = (size_t)(row >> 4) * 4 * 2048;
    int within = ((row & 15) + ((l >> 3) & 3) * 16) * 32 + (l & 7) * 4;
    int kc0 = l >> 5;          // k=4l       -> kc in {0,1}
    int kc1 = (l >> 5) + 2;    // k=4l+256   -> kc in {2,3}
    *(int*)(nf8 + base + (size_t)kc0 * 2048 + within) = pk0;
    *(int*)(nf8 + base + (size_t)kc1 * 2048 + within) = pk1;
    if (l == 0) sq[row] = s * rn * rn;
}

__device__ __forceinline__ void decode_tile(int u, int& ti, int& tj) {
    // u = tj*(tj+1)/2 + ti, ti <= tj
    int t = (int)((sqrtf(8.0f * (float)u + 1.0f) - 1.0f) * 0.5f);
    while ((t + 1) * (t + 2) / 2 <= u) ++t;
    while (t * (t + 1) / 2 > u) --t;
    tj = t;
    ti = u - t * (t + 1) / 2;
}

// Kernel 2: 128x128 block-tiles (4 waves x one 64x64 quadrant).
// Round-6 change: fragment-major nf8 layout ->
//  * B frags read DIRECTLY from global (contiguous 2 KB/wave, L1-shared by
//    wave pairs + co-resident blocks): no B staging, no B ds_reads.
//  * A staged via global_load_lds (4 x 1 KB DMA per wave per chunk) into a
//    halved 2x16 KB double buffer -> LDS 33 KB -> 3 blocks/CU (VGPR-capped),
//    1.5x the wave count of rounds 4/5.
// Counted-vmcnt schedule per chunk: [bf loads(8)] [stage(c+1) DMA(4)]
// vmcnt(12) (own stage(c) landed; bf+next-DMA stay outstanding); barrier;
// ds_read A + MFMA (backend waits bf at vmcnt(4): prefetch DMAs NOT drained);
// barrier. sched_barrier(0) pins bf-before-stage issue order so the
// accounting holds.
__global__ __launch_bounds__(256, 3) void gram_hinge(
    const unsigned char* __restrict__ nf8, const float* __restrict__ sq,
    const int* __restrict__ y, double* __restrict__ part,
    unsigned int* __restrict__ counter, float* __restrict__ out)
{
    __shared__ unsigned char As[2][16384];   // 32 KB: A half-tile frags, dbuf
    __shared__ float wpart[4];
    __shared__ double dpart[4];
    __shared__ int is_last;

    int tid = threadIdx.x;
    int w = tid >> 6, l = tid & 63;
    int wr = w >> 1, wc = w & 1;      // wave quadrant in 128x128 tile
    int lr = l & 15, q = l >> 4;

    // stage one chunk of A (8 frags = 16 KB) into dAb: 4 x 1 KB DMA per wave.
    // instr t = w*4+i covers frag rf=t>>1, half=t&1; LDS = linear blob concat.
    auto stageA = [&](unsigned char* dAb, int pti, int pc) {
        #pragma unroll
        for (int i = 0; i < 4; ++i) {
            int t = w * 4 + i;
            int rf = t >> 1, half = t & 1;
            const unsigned char* src = nf8
                + ((size_t)((pti * 8 + rf) * 4 + pc)) * 2048 + half * 1024 + l * 16;
            __builtin_amdgcn_global_load_lds(
                (const __attribute__((address_space(1))) void*)src,
                (__attribute__((address_space(3))) void*)(dAb + t * 1024), 16, 0, 0);
        }
    };

    float acc0 = 0.f, acc1 = 0.f, acc2 = 0.f, acc3 = 0.f;

    int u = blockIdx.x;
    int ti, tj;
    decode_tile(u, ti, tj);

    // prologue: stage (tile u, chunk 0) into buffer 0 (verified at first vmcnt)
    stageA(As[0], ti, 0);

    while (u < NUPPER) {
        int u_next = u + GRID;
        bool have_next = (u_next < NUPPER);
        int ti_n = 0, tj_n = 0;
        if (have_next) decode_tile(u_next, ti_n, tj_n);

        f32x4 accv[4][4] = {};

        #pragma unroll 1
        for (int c = 0; c < 4; ++c) {
            // ---- B frags for chunk c: direct contiguous reads (L1/L2) ----
            i32x8 bf[4];
            #pragma unroll
            for (int ni = 0; ni < 4; ++ni)
                bf[ni] = *(const i32x8*)(nf8
                    + ((size_t)((tj * 8 + wc * 4 + ni) * 4 + c)) * 2048 + l * 32);
            __builtin_amdgcn_sched_barrier(0);   // keep bf issued before DMA

            // ---- issue next A-stage (stays in flight across barriers) ----
            if (c < 3) {
                stageA(As[(c + 1) & 1], ti, c + 1);
                asm volatile("s_waitcnt vmcnt(12)" ::: "memory"); // stage(c) landed
            } else if (have_next) {
                stageA(As[0], ti_n, 0);
                asm volatile("s_waitcnt vmcnt(12)" ::: "memory"); // stage(c) landed
            } else {
                asm volatile("s_waitcnt vmcnt(8)" ::: "memory");  // no newer stage
            }
            asm volatile("s_barrier" ::: "memory");   // all waves' stage(c) landed

            // ---- compute chunk c: A frags from LDS buffer c&1 ----
            const unsigned char* Ab = As[c & 1];
            __builtin_amdgcn_s_setprio(1);
            #pragma unroll
            for (int mi = 0; mi < 4; ++mi) {
                i32x8 af = *(const i32x8*)(Ab + (wr * 4 + mi) * 2048 + l * 32);
                #pragma unroll
                for (int ni = 0; ni < 4; ++ni)
                    accv[mi][ni] = __builtin_amdgcn_mfma_scale_f32_16x16x128_f8f6f4(
                        af, bf[ni], accv[mi][ni],
                        0, 0, 0, 0x7F7F7F7F, 0, 0x7F7F7F7F);
            }
            __builtin_amdgcn_s_setprio(0);

            // all waves' A-reads of buf c&1 done before next chunk's overwrite
            asm volatile("s_barrier" ::: "memory");
        }

        // ---- per-tile epilogue (C/D layout: col=lane&15 -> j, row=q*4+reg -> i) ----
        {
            int jb = tj * 128 + wc * 64 + lr;
            float sqj[4]; int yj[4];
            #pragma unroll
            for (int ni = 0; ni < 4; ++ni) {
                sqj[ni] = sq[jb + ni * 16];
                yj[ni]  = y[jb + ni * 16];
            }
            bool skip = (ti == tj) && (wr > wc);        // strictly below diag
            bool full = (ti != tj) || (wc > wr);        // fully above diag
            if (!skip) {
                if (full) {
                    #pragma unroll
                    for (int mi = 0; mi < 4; ++mi) {
                        #pragma unroll
                        for (int r = 0; r < 4; ++r) {
                            int ia = ti * 128 + wr * 64 + mi * 16 + q * 4 + r;
                            float ci = THETA - sq[ia];
                            int yi = y[ia];
                            float h0 = fmaxf(fmaf(2.f, accv[mi][0][r], ci - sqj[0]), 0.f);
                            acc0 += (yi == yj[0]) ? h0 : -h0;
                            float h1 = fmaxf(fmaf(2.f, accv[mi][1][r], ci - sqj[1]), 0.f);
                            acc1 += (yi == yj[1]) ? h1 : -h1;
                            float h2 = fmaxf(fmaf(2.f, accv[mi][2][r], ci - sqj[2]), 0.f);
                            acc2 += (yi == yj[2]) ? h2 : -h2;
                            float h3 = fmaxf(fmaf(2.f, accv[mi][3][r], ci - sqj[3]), 0.f);
                            acc3 += (yi == yj[3]) ? h3 : -h3;
                        }
                    }
                } else {
                    // diagonal quadrant (wr==wc): count local col >= local row
                    #pragma unroll
                    for (int mi = 0; mi < 4; ++mi) {
                        #pragma unroll
                        for (int r = 0; r < 4; ++r) {
                            int rl_ = mi * 16 + q * 4 + r;
                            int ia = ti * 128 + wr * 64 + rl_;
                            float ci = THETA - sq[ia];
                            int yi = y[ia];
                            #pragma unroll
                            for (int ni = 0; ni < 4; ++ni) {
                                float h = fmaxf(fmaf(2.f, accv[mi][ni][r], ci - sqj[ni]), 0.f);
                                float sh = (yi == yj[ni]) ? h : -h;
                                if (ni * 16 + lr >= rl_) acc0 += sh;
                            }
                        }
                    }
                }
            }
        }

        u = u_next; ti = ti_n; tj = tj_n;
    }

    float local = (acc0 + acc1) + (acc2 + acc3);
    #pragma unroll
    for (int off = 32; off > 0; off >>= 1) local += __shfl_down(local, off);
    if (l == 0) wpart[w] = local;
    __syncthreads();
    if (tid == 0) {
        double ssum = (double)wpart[0] + (double)wpart[1]
                    + (double)wpart[2] + (double)wpart[3];
        __hip_atomic_store(&part[blockIdx.x], ssum, __ATOMIC_RELEASE, __HIP_MEMORY_SCOPE_AGENT);
        unsigned int ticket = __hip_atomic_fetch_add(
            counter, 1u, __ATOMIC_ACQ_REL, __HIP_MEMORY_SCOPE_AGENT);
        is_last = (ticket == GRID - 1) ? 1 : 0;
    }
    __syncthreads();
    if (is_last) {
        double s = 0.0;
        for (int i = tid; i < GRID; i += 256)
            s += __hip_atomic_load(&part[i], __ATOMIC_ACQUIRE, __HIP_MEMORY_SCOPE_AGENT);
        #pragma unroll
        for (int off = 32; off > 0; off >>= 1) s += __shfl_down(s, off);
        if (l == 0) dpart[w] = s;
        __syncthreads();
        if (tid == 0) {
            // add the analytically-known XI term: XI * #upper-tri pairs
            double total = (dpart[0] + dpart[1] + dpart[2] + dpart[3])
                         + (double)XI * NPAIRS_UP;
            const double m = 1.0 / ((double)BDIM * (double)BDIM - (double)BDIM);
            out[0] = (float)(total * m);
        }
    }
}

extern "C" void kernel_launch(void* const* d_in, const int* in_sizes, int n_in,
                              void* d_out, int out_size, void* d_ws, size_t ws_size,
                              hipStream_t stream) {
    const float* x = (const float*)d_in[0];
    const int* y = (const int*)d_in[1];
    float* out = (float*)d_out;

    unsigned char* nf8 = (unsigned char*)d_ws;                          // 4 MB fp8 (tiled)
    char* p = (char*)d_ws + (size_t)BDIM * DDIM;
    float* sq = (float*)p;                                              // 32 KB
    unsigned int* counter = (unsigned int*)(p + (size_t)BDIM * 4);
    double* part = (double*)(p + (size_t)BDIM * 4 + 64);                // GRID doubles

    normalize_rows<<<BDIM / 4, 256, 0, stream>>>(x, nf8, sq, counter);
    gram_hinge<<<GRID, 256, 0, stream>>>(nf8, sq, y, part, counter, out);
}